// Round 15
// baseline (74.251 us; speedup 1.0000x reference)
//
#include <hip/hip_runtime.h>

// CARAFE: x(8,256,64,64) fp32
//   -> conv1x1 (256->64) swapped-operand bf16 MFMA (+ Bp prep trailing) -> comp bf16 NHWC
//   -> conv3x3 (64->100) bf16 MFMA, B staged in LDS (3-step phases) + softmax, packed mask
//   -> reassembly (d-outer/p-inner, packed bpermute, pk_fma, nt stores) -> out fp32
// K=5, G=1, S=2.
// maskP layout: [nimg][h][n2(50)][w] uint, n2=2t+spq, pair=(sp=2spq, sp=2spq+1) bf16 (lo,hi).

#define CI 256

typedef __attribute__((ext_vector_type(8))) short bf16x8;
typedef __attribute__((ext_vector_type(4))) float f32x4;
typedef __attribute__((ext_vector_type(2))) float f32x2;

__device__ inline unsigned short f2bf(float f) {
    unsigned u = __float_as_uint(f);
    unsigned r = (u + 0x7FFF + ((u >> 16) & 1)) >> 16;
    return (unsigned short)r;
}

__device__ inline unsigned cvt_pk_bf16(float lo, float hi) {
    unsigned r;
    asm("v_cvt_pk_bf16_f32 %0, %1, %2" : "=v"(r) : "v"(lo), "v"(hi));
    return r;
}

__device__ inline float bf_lo(unsigned u) { return __int_as_float(u << 16); }
__device__ inline float bf_hi(unsigned u) { return __int_as_float(u & 0xffff0000u); }

// acc.lo += m.lo * s.lo ; acc.hi += m.hi * s.lo   (broadcast s.lo)
__device__ inline void pk_fma_lo(f32x2& acc, f32x2 m, f32x2 s) {
    asm("v_pk_fma_f32 %0, %1, %2, %0 op_sel_hi:[1,0,1]" : "+v"(acc) : "v"(m), "v"(s));
}
// acc.lo += m.lo * s.hi ; acc.hi += m.hi * s.hi   (broadcast s.hi)
__device__ inline void pk_fma_hi(f32x2& acc, f32x2 m, f32x2 s) {
    asm("v_pk_fma_f32 %0, %1, %2, %0 op_sel:[0,1,0] op_sel_hi:[1,1,1]" : "+v"(acc) : "v"(m), "v"(s));
}

__device__ inline void nt_store2(float* p, f32x2 v) {
    __builtin_nontemporal_store(__builtin_bit_cast(unsigned long long, v),
                                (unsigned long long*)p);
}

// ---------------- kernel 0: small prep (wA, zp only — conv1x1 reads these) ----------------
__global__ __launch_bounds__(256) void prep_small(const float* __restrict__ w_comp,
                                                  unsigned short* __restrict__ wA,
                                                  float* __restrict__ zp) {
    int i = blockIdx.x * 256 + threadIdx.x;
    if (i < 64) zp[i] = 0.f;
    if (i < 64 * 256) wA[i] = f2bf(w_comp[i]);
}

// ---------------- kernel 1: 1x1 conv via MFMA + Bp prep in trailing blocks ----------------
__global__ __launch_bounds__(64) void conv1x1_mfma(const float* __restrict__ x,
                                                   const unsigned short* __restrict__ wA,
                                                   const float* __restrict__ b_comp,
                                                   const float* __restrict__ w_enc,
                                                   unsigned short* __restrict__ comp,
                                                   unsigned short* __restrict__ Bp) {
    int l = threadIdx.x;
    int b = blockIdx.x;

    if (b >= 2048) {
        int idx = (b - 2048) * 64 + l;      // < 72*112*8 = 64512
        int j = idx & 7;
        int n = (idx >> 3) % 112;
        int g = idx / (112 * 8);
        int k = g * 8 + j;
        int tap = k >> 6;
        int c = k & 63;
        float v = (n < 100) ? w_enc[n * 576 + c * 9 + tap] : 0.f;
        Bp[idx] = f2bf(v);
        return;
    }

    int c16 = l & 15;
    int lq  = l >> 4;
    int bs  = (b & 7) * 256 + (b >> 3);   // bijective: 2048 = 8*256
    int P0  = bs * 16;
    int nimg = P0 >> 12;
    int hw   = P0 & 4095;

    const float* xp = x + (size_t)nimg * CI * 4096 + hw + c16;

    f32x4 acc[4];
#pragma unroll
    for (int mt = 0; mt < 4; mt++) acc[mt] = f32x4{0.f, 0.f, 0.f, 0.f};

#pragma unroll
    for (int ks = 0; ks < 8; ks++) {
        int k0 = ks * 32 + lq * 8;
        float v[8];
#pragma unroll
        for (int j = 0; j < 8; j++) v[j] = xp[(size_t)(k0 + j) * 4096];
        bf16x8 xb;
#pragma unroll
        for (int j = 0; j < 8; j++) xb[j] = (short)f2bf(v[j]);
#pragma unroll
        for (int mt = 0; mt < 4; mt++) {
            bf16x8 wf = *(const bf16x8*)(wA + (mt * 16 + c16) * 256 + k0);
            acc[mt] = __builtin_amdgcn_mfma_f32_16x16x32_bf16(wf, xb, acc[mt], 0, 0, 0);
        }
    }

    unsigned short* cp = comp + (size_t)(P0 + c16) * 64;
#pragma unroll
    for (int mt = 0; mt < 4; mt++) {
        int och0 = mt * 16 + lq * 4;
        float4 bb = *reinterpret_cast<const float4*>(b_comp + och0);
        unsigned u0 = f2bf(acc[mt][0] + bb.x) | (f2bf(acc[mt][1] + bb.y) << 16);
        unsigned u1 = f2bf(acc[mt][2] + bb.z) | (f2bf(acc[mt][3] + bb.w) << 16);
        reinterpret_cast<uint2*>(cp + och0)[0] = uint2{u0, u1};
    }
}

// ---------------- kernel 2: 3x3 conv, B staged in LDS (3 K-steps/phase) ----------------
__global__ __launch_bounds__(256) void conv3x3_mfma(const unsigned short* __restrict__ comp,
                                                    const unsigned short* __restrict__ Bp,
                                                    const float* __restrict__ b_enc,
                                                    const float* __restrict__ zp,
                                                    unsigned* __restrict__ maskP) {
    __shared__ char Bs[2][3 * 7168];
    int tid = threadIdx.x;
    int wv  = tid >> 6;          // 0..3 (wave id)
    int l   = tid & 63;
    int c16 = l & 15;
    int lq  = l >> 4;
    int b   = blockIdx.x;
    int bs  = (b & 7) * 64 + (b >> 3);   // bijective: 512 = 8*64
    int nimg = bs >> 6;
    int h    = bs & 63;
    int w0   = wv * 16;

    const char* cbase = (const char*)(comp + (size_t)nimg * 4096 * 64);
    const char* zpb   = (const char*)zp;
    const char* Bpb   = (const char*)Bp;

#define STAGEPH(s0_, buf_)                                                                \
    {                                                                                     \
        const char* src_ = Bpb + (s0_)*7168 + l * 16;                                     \
        for (int inst_ = wv; inst_ < 21; inst_ += 4) {                                    \
            __builtin_amdgcn_global_load_lds(                                             \
                (const __attribute__((address_space(1))) void*)(src_ + inst_ * 1024),     \
                (__attribute__((address_space(3))) void*)(&Bs[buf_][inst_ * 1024]),       \
                16, 0, 0);                                                                \
        }                                                                                 \
    }

    f32x4 acc[7];
#pragma unroll
    for (int nt = 0; nt < 7; nt++) acc[nt] = f32x4{0.f, 0.f, 0.f, 0.f};

    const int dyt[9] = {-1, -1, -1, 0, 0, 0, 1, 1, 1};
    const int dxt[9] = {-1, 0, 1, -1, 0, 1, -1, 0, 1};

    STAGEPH(0, 0);
    __syncthreads();

#pragma unroll
    for (int ph = 0; ph < 6; ph++) {
        int s0  = ph * 3;
        int cur = ph & 1;
        if (ph < 5) STAGEPH(s0 + 3, cur ^ 1);
        for (int ss = 0; ss < 3; ss++) {
            int s = s0 + ss;
            int tap = s >> 1, half = s & 1;
            int hh = h + dyt[tap];
            int ww = w0 + c16 + dxt[tap];
            const char* ap = ((unsigned)hh < 64u && (unsigned)ww < 64u)
                                 ? cbase + (hh * 64 + ww) * 128 : zpb;
            bf16x8 a = *(const bf16x8*)(ap + lq * 16 + half * 64);

            bf16x8 bf[7];
#pragma unroll
            for (int nt = 0; nt < 7; nt++)
                bf[nt] = *(const bf16x8*)(&Bs[cur][ss * 7168 + (lq * 112 + nt * 16 + c16) * 16]);
#pragma unroll
            for (int nt = 0; nt < 7; nt++)
                acc[nt] = __builtin_amdgcn_mfma_f32_16x16x32_bf16(a, bf[nt], acc[nt], 0, 0, 0);
        }
        __syncthreads();
    }
#undef STAGEPH

    float bias[7];
#pragma unroll
    for (int nt = 0; nt < 7; nt++) {
        int n = nt * 16 + c16;
        bias[nt] = (n < 100) ? b_enc[n] : 0.f;
    }
    int nvalid = (c16 < 4) ? 7 : 6;

    unsigned* mbase = maskP + ((size_t)nimg * 64 + h) * 3200;

#pragma unroll
    for (int r = 0; r < 4; r++) {
        float v[7];
#pragma unroll
        for (int nt = 0; nt < 7; nt++) v[nt] = acc[nt][r] + bias[nt];
        float m = v[0];
#pragma unroll
        for (int nt = 1; nt < 7; nt++) if (nt < nvalid) m = fmaxf(m, v[nt]);
        m = fmaxf(m, __shfl_xor(m, 4));
        m = fmaxf(m, __shfl_xor(m, 8));
        float e[7];
        float s = 0.f;
#pragma unroll
        for (int nt = 0; nt < 7; nt++) {
            e[nt] = (nt < nvalid) ? __expf(v[nt] - m) : 0.f;
            s += e[nt];
        }
        s += __shfl_xor(s, 4);
        s += __shfl_xor(s, 8);
        float inv = 1.f / s;
        int wpix = w0 + lq * 4 + r;
#pragma unroll
        for (int nt = 0; nt < 7; nt++) {
            float mine = (nt < nvalid) ? e[nt] * inv : 0.f;
            float part = __shfl_xor(mine, 1);
            if (((c16 & 1) == 0) && (nt * 16 + c16) < 100) {
                unsigned pk = cvt_pk_bf16(mine, part);
                mbase[(nt * 8 + (c16 >> 1)) * 64 + wpix] = pk;
            }
        }
    }
}

// ---------------- kernel 3: reassembly (d-outer / p-inner, pk_fma, nt stores) ----------------
// Per tap-row d: load 10 mask words (20 VGPR live, not 100), then 8 INDEPENDENT
// channel-pair chains (8 x-loads + 32 bpermutes in flight). acc[8][4] f32x2 = 64 VGPR,
// statically indexed. Same instruction counts as R12; ~4 waves/SIMD and deep DS ILP.
__global__ __launch_bounds__(256) void reassemble(const float* __restrict__ x,
                                                  const unsigned* __restrict__ maskP,
                                                  float* __restrict__ out) {
    int lane = threadIdx.x & 63;       // = w
    int cq   = threadIdx.x >> 6;       // 0..3, wave-uniform
    int b    = blockIdx.x;
    int bs   = (b & 7) * 256 + (b >> 3);   // bijective: 2048 = 8*256
    int cgb  = bs & 3;
    int h    = (bs >> 2) & 63;
    int n    = bs >> 8;
    int c0   = cgb * 64 + cq * 16;

    const unsigned* mrow = maskP + ((size_t)n * 64 + h) * 3200 + lane;

    int idxm2 = ((lane - 2) & 63) << 2;
    int idxm1 = ((lane - 1) & 63) << 2;
    int idxp1 = ((lane + 1) & 63) << 2;
    int idxp2 = ((lane + 2) & 63) << 2;

    const float* xbase = x + ((size_t)(n * CI + c0)) * 4096 + lane;
    float*       obase = out + ((size_t)(n * CI + c0) * 128 + 2 * h) * 128 + 2 * lane;

    float vmx[5];
#pragma unroll
    for (int d = 0; d < 5; d++) {
        int xc = lane + d - 2;
        vmx[d] = ((unsigned)xc < 64u) ? 1.f : 0.f;
    }

    // accumulators: [pair p][A0,A1,B0,B1]
    f32x2 acc[8][4];
#pragma unroll
    for (int p = 0; p < 8; p++)
#pragma unroll
        for (int q = 0; q < 4; q++) acc[p][q] = f32x2{0.f, 0.f};

#pragma unroll
    for (int d = 0; d < 5; d++) {
        int y   = h + d - 2;
        int yo  = min(max(y, 0), 63) * 64;
        float fy = ((unsigned)y < 64u) ? 1.f : 0.f;

        // load + fold this tap-row's 10 mask words
        f32x2 mskd[10];
#pragma unroll
        for (int k = 0; k < 5; k++) {
            int t = d * 5 + k;
            float f = fy * vmx[k];
            unsigned u0 = mrow[(2 * t + 0) * 64];
            unsigned u1 = mrow[(2 * t + 1) * 64];
            f32x2 m01, m23;
            m01.x = bf_lo(u0); m01.y = bf_hi(u0);
            m23.x = bf_lo(u1); m23.y = bf_hi(u1);
            mskd[2 * k + 0] = m01 * f;
            mskd[2 * k + 1] = m23 * f;
        }

#pragma unroll
        for (int p = 0; p < 8; p++) {
            const float* xc = xbase + (size_t)(2 * p) * 4096;
            float ra = xc[yo];
            float rb = xc[4096 + yo];
            int pv = (int)cvt_pk_bf16(ra, rb);
            int sm2 = __builtin_amdgcn_ds_bpermute(idxm2, pv);
            int sm1 = __builtin_amdgcn_ds_bpermute(idxm1, pv);
            int sp1 = __builtin_amdgcn_ds_bpermute(idxp1, pv);
            int sp2 = __builtin_amdgcn_ds_bpermute(idxp2, pv);
            f32x2 s[5];
            s[0].x = bf_lo((unsigned)sm2); s[0].y = bf_hi((unsigned)sm2);
            s[1].x = bf_lo((unsigned)sm1); s[1].y = bf_hi((unsigned)sm1);
            s[2].x = ra;                   s[2].y = rb;
            s[3].x = bf_lo((unsigned)sp1); s[3].y = bf_hi((unsigned)sp1);
            s[4].x = bf_lo((unsigned)sp2); s[4].y = bf_hi((unsigned)sp2);
#pragma unroll
            for (int k = 0; k < 5; k++) {
                pk_fma_lo(acc[p][0], mskd[2 * k + 0], s[k]);   // chA rows 0
                pk_fma_lo(acc[p][1], mskd[2 * k + 1], s[k]);   // chA rows 1
                pk_fma_hi(acc[p][2], mskd[2 * k + 0], s[k]);   // chB rows 0
                pk_fma_hi(acc[p][3], mskd[2 * k + 1], s[k]);   // chB rows 1
            }
        }
    }

#pragma unroll
    for (int p = 0; p < 8; p++) {
        float* opa = obase + (size_t)(2 * p) * 16384;
        float* opb = opa + 16384;
        nt_store2(opa,       acc[p][0]);
        nt_store2(opa + 128, acc[p][1]);
        nt_store2(opb,       acc[p][2]);
        nt_store2(opb + 128, acc[p][3]);
    }
}

extern "C" void kernel_launch(void* const* d_in, const int* in_sizes, int n_in,
                              void* d_out, int out_size, void* d_ws, size_t ws_size,
                              hipStream_t stream) {
    const float* x      = (const float*)d_in[0];
    const float* w_comp = (const float*)d_in[1];
    const float* b_comp = (const float*)d_in[2];
    const float* w_enc  = (const float*)d_in[3];
    const float* b_enc  = (const float*)d_in[4];
    float* out = (float*)d_out;

    // workspace layout (bytes)
    char* ws = (char*)d_ws;
    float*          zp    = (float*)(ws + 0);                 // 256 B zeros
    unsigned short* wA    = (unsigned short*)(ws + 256);      // 32768 B
    unsigned short* Bp    = (unsigned short*)(ws + 33024);    // 129024 B
    unsigned short* comp  = (unsigned short*)(ws + 162048);   // 4 MB
    unsigned*       maskP = (unsigned*)(ws + 4356352);        // 6.55 MB
    // total ~11 MB

    prep_small<<<64, 256, 0, stream>>>(w_comp, wA, zp);
    conv1x1_mfma<<<2048 + 1008, 64, 0, stream>>>(x, wA, b_comp, w_enc, comp, Bp);
    conv3x3_mfma<<<512, 256, 0, stream>>>(comp, Bp, b_enc, zp, maskP);
    reassemble<<<2048, 256, 0, stream>>>(x, maskP, out);
}

// Round 16
// 65.867 us; speedup vs baseline: 1.1273x; 1.1273x over previous
//
#include <hip/hip_runtime.h>

// CARAFE: x(8,256,64,64) fp32
//   -> conv1x1 (256->64) bf16 MFMA, 32 px/wave (128B-line A-loads) + Bp prep trailing
//   -> conv3x3 (64->100) bf16 MFMA, B staged in LDS (5-step phases) + softmax, packed mask
//   -> reassembly (merged sp rows, packed bpermute, pk_fma, nt stores) -> out fp32
// K=5, G=1, S=2.
// maskP layout: [nimg][h][n2(50)][w] uint, n2=2t+spq, pair=(sp=2spq, sp=2spq+1) bf16 (lo,hi).

#define CI 256

typedef __attribute__((ext_vector_type(8))) short bf16x8;
typedef __attribute__((ext_vector_type(4))) float f32x4;
typedef __attribute__((ext_vector_type(2))) float f32x2;

__device__ inline unsigned short f2bf(float f) {
    unsigned u = __float_as_uint(f);
    unsigned r = (u + 0x7FFF + ((u >> 16) & 1)) >> 16;
    return (unsigned short)r;
}

__device__ inline unsigned cvt_pk_bf16(float lo, float hi) {
    unsigned r;
    asm("v_cvt_pk_bf16_f32 %0, %1, %2" : "=v"(r) : "v"(lo), "v"(hi));
    return r;
}

__device__ inline float bf_lo(unsigned u) { return __int_as_float(u << 16); }
__device__ inline float bf_hi(unsigned u) { return __int_as_float(u & 0xffff0000u); }

// acc.lo += m.lo * s.lo ; acc.hi += m.hi * s.lo   (broadcast s.lo)
__device__ inline void pk_fma_lo(f32x2& acc, f32x2 m, f32x2 s) {
    asm("v_pk_fma_f32 %0, %1, %2, %0 op_sel_hi:[1,0,1]" : "+v"(acc) : "v"(m), "v"(s));
}
// acc.lo += m.lo * s.hi ; acc.hi += m.hi * s.hi   (broadcast s.hi)
__device__ inline void pk_fma_hi(f32x2& acc, f32x2 m, f32x2 s) {
    asm("v_pk_fma_f32 %0, %1, %2, %0 op_sel:[0,1,0] op_sel_hi:[1,1,1]" : "+v"(acc) : "v"(m), "v"(s));
}

__device__ inline void nt_store2(float* p, f32x2 v) {
    __builtin_nontemporal_store(__builtin_bit_cast(unsigned long long, v),
                                (unsigned long long*)p);
}

// ---------------- kernel 0: small prep (wA, zp only — conv1x1 reads these) ----------------
__global__ __launch_bounds__(256) void prep_small(const float* __restrict__ w_comp,
                                                  unsigned short* __restrict__ wA,
                                                  float* __restrict__ zp) {
    int i = blockIdx.x * 256 + threadIdx.x;
    if (i < 64) zp[i] = 0.f;
    if (i < 64 * 256) wA[i] = f2bf(w_comp[i]);
}

// ---------------- kernel 1: 1x1 conv via MFMA, 32 px/wave ----------------
// Wave covers pixels [P0, P0+32): A-loads for the two 16-px tiles are adjacent,
// so each k-slice reads 32*4B = 128B = one full cache line (no over-fetch).
// wA B-fragment reused for both pixel tiles. Trailing 1008 blocks do Bp prep.
__global__ __launch_bounds__(64) void conv1x1_mfma(const float* __restrict__ x,
                                                   const unsigned short* __restrict__ wA,
                                                   const float* __restrict__ b_comp,
                                                   const float* __restrict__ w_enc,
                                                   unsigned short* __restrict__ comp,
                                                   unsigned short* __restrict__ Bp) {
    int l = threadIdx.x;
    int b = blockIdx.x;

    if (b >= 1024) {
        int idx = (b - 1024) * 64 + l;      // 1008*64 = 64512 = 72*112*8
        int j = idx & 7;
        int n = (idx >> 3) % 112;
        int g = idx / (112 * 8);
        int k = g * 8 + j;
        int tap = k >> 6;
        int c = k & 63;
        float v = (n < 100) ? w_enc[n * 576 + c * 9 + tap] : 0.f;
        Bp[idx] = f2bf(v);
        return;
    }

    int c16 = l & 15;
    int lq  = l >> 4;
    int bs  = (b & 7) * 128 + (b >> 3);   // bijective: 1024 = 8*128
    int P0  = bs * 32;
    int nimg = P0 >> 12;
    int hw   = P0 & 4095;

    const float* xp = x + (size_t)nimg * CI * 4096 + hw + c16;

    f32x4 acc[4][2];
#pragma unroll
    for (int mt = 0; mt < 4; mt++)
#pragma unroll
        for (int pt = 0; pt < 2; pt++) acc[mt][pt] = f32x4{0.f, 0.f, 0.f, 0.f};

#pragma unroll
    for (int ks = 0; ks < 8; ks++) {
        int k0 = ks * 32 + lq * 8;
        float v0[8], v1[8];
#pragma unroll
        for (int j = 0; j < 8; j++) {
            const float* pj = xp + (size_t)(k0 + j) * 4096;
            v0[j] = pj[0];
            v1[j] = pj[16];
        }
        bf16x8 xb0, xb1;
#pragma unroll
        for (int j = 0; j < 8; j++) {
            xb0[j] = (short)f2bf(v0[j]);
            xb1[j] = (short)f2bf(v1[j]);
        }
#pragma unroll
        for (int mt = 0; mt < 4; mt++) {
            bf16x8 wf = *(const bf16x8*)(wA + (mt * 16 + c16) * 256 + k0);
            acc[mt][0] = __builtin_amdgcn_mfma_f32_16x16x32_bf16(wf, xb0, acc[mt][0], 0, 0, 0);
            acc[mt][1] = __builtin_amdgcn_mfma_f32_16x16x32_bf16(wf, xb1, acc[mt][1], 0, 0, 0);
        }
    }

#pragma unroll
    for (int pt = 0; pt < 2; pt++) {
        unsigned short* cp = comp + (size_t)(P0 + pt * 16 + c16) * 64;
#pragma unroll
        for (int mt = 0; mt < 4; mt++) {
            int och0 = mt * 16 + lq * 4;
            float4 bb = *reinterpret_cast<const float4*>(b_comp + och0);
            unsigned u0 = f2bf(acc[mt][pt][0] + bb.x) | (f2bf(acc[mt][pt][1] + bb.y) << 16);
            unsigned u1 = f2bf(acc[mt][pt][2] + bb.z) | (f2bf(acc[mt][pt][3] + bb.w) << 16);
            reinterpret_cast<uint2*>(cp + och0)[0] = uint2{u0, u1};
        }
    }
}

// ---------------- kernel 2: 3x3 conv, B staged in LDS (5 K-steps/phase) ----------------
__global__ __launch_bounds__(256) void conv3x3_mfma(const unsigned short* __restrict__ comp,
                                                    const unsigned short* __restrict__ Bp,
                                                    const float* __restrict__ b_enc,
                                                    const float* __restrict__ zp,
                                                    unsigned* __restrict__ maskP) {
    __shared__ char Bs[2][5 * 7168];
    int tid = threadIdx.x;
    int wv  = tid >> 6;          // 0..3 (wave id)
    int l   = tid & 63;
    int c16 = l & 15;
    int lq  = l >> 4;
    int b   = blockIdx.x;
    int bs  = (b & 7) * 64 + (b >> 3);   // bijective: 512 = 8*64
    int nimg = bs >> 6;
    int h    = bs & 63;
    int w0   = wv * 16;

    const char* cbase = (const char*)(comp + (size_t)nimg * 4096 * 64);
    const char* zpb   = (const char*)zp;
    const char* Bpb   = (const char*)Bp;

#define STAGEPH(s0_, cnt_, buf_)                                                          \
    {                                                                                     \
        const char* src_ = Bpb + (s0_)*7168 + l * 16;                                     \
        for (int inst_ = wv; inst_ < 7 * (cnt_); inst_ += 4) {                            \
            __builtin_amdgcn_global_load_lds(                                             \
                (const __attribute__((address_space(1))) void*)(src_ + inst_ * 1024),     \
                (__attribute__((address_space(3))) void*)(&Bs[buf_][inst_ * 1024]),       \
                16, 0, 0);                                                                \
        }                                                                                 \
    }

    f32x4 acc[7];
#pragma unroll
    for (int nt = 0; nt < 7; nt++) acc[nt] = f32x4{0.f, 0.f, 0.f, 0.f};

    const int dyt[9] = {-1, -1, -1, 0, 0, 0, 1, 1, 1};
    const int dxt[9] = {-1, 0, 1, -1, 0, 1, -1, 0, 1};

    STAGEPH(0, 5, 0);
    __syncthreads();

#pragma unroll
    for (int ph = 0; ph < 4; ph++) {
        int s0  = ph * 5;
        int cnt = (s0 + 5 <= 18) ? 5 : (18 - s0);
        int cur = ph & 1;
        if (ph < 3) {
            int ns0  = s0 + 5;
            int ncnt = (ns0 + 5 <= 18) ? 5 : (18 - ns0);
            STAGEPH(ns0, ncnt, cur ^ 1);
        }
        for (int ss = 0; ss < cnt; ss++) {
            int s = s0 + ss;
            int tap = s >> 1, half = s & 1;
            int hh = h + dyt[tap];
            int ww = w0 + c16 + dxt[tap];
            const char* ap = ((unsigned)hh < 64u && (unsigned)ww < 64u)
                                 ? cbase + (hh * 64 + ww) * 128 : zpb;
            bf16x8 a = *(const bf16x8*)(ap + lq * 16 + half * 64);

            bf16x8 bf[7];
#pragma unroll
            for (int nt = 0; nt < 7; nt++)
                bf[nt] = *(const bf16x8*)(&Bs[cur][ss * 7168 + (lq * 112 + nt * 16 + c16) * 16]);
#pragma unroll
            for (int nt = 0; nt < 7; nt++)
                acc[nt] = __builtin_amdgcn_mfma_f32_16x16x32_bf16(a, bf[nt], acc[nt], 0, 0, 0);
        }
        __syncthreads();
    }
#undef STAGEPH

    float bias[7];
#pragma unroll
    for (int nt = 0; nt < 7; nt++) {
        int n = nt * 16 + c16;
        bias[nt] = (n < 100) ? b_enc[n] : 0.f;
    }
    int nvalid = (c16 < 4) ? 7 : 6;

    unsigned* mbase = maskP + ((size_t)nimg * 64 + h) * 3200;

#pragma unroll
    for (int r = 0; r < 4; r++) {
        float v[7];
#pragma unroll
        for (int nt = 0; nt < 7; nt++) v[nt] = acc[nt][r] + bias[nt];
        float m = v[0];
#pragma unroll
        for (int nt = 1; nt < 7; nt++) if (nt < nvalid) m = fmaxf(m, v[nt]);
        m = fmaxf(m, __shfl_xor(m, 4));
        m = fmaxf(m, __shfl_xor(m, 8));
        float e[7];
        float s = 0.f;
#pragma unroll
        for (int nt = 0; nt < 7; nt++) {
            e[nt] = (nt < nvalid) ? __expf(v[nt] - m) : 0.f;
            s += e[nt];
        }
        s += __shfl_xor(s, 4);
        s += __shfl_xor(s, 8);
        float inv = 1.f / s;
        int wpix = w0 + lq * 4 + r;
#pragma unroll
        for (int nt = 0; nt < 7; nt++) {
            float mine = (nt < nvalid) ? e[nt] * inv : 0.f;
            float part = __shfl_xor(mine, 1);
            if (((c16 & 1) == 0) && (nt * 16 + c16) < 100) {
                unsigned pk = cvt_pk_bf16(mine, part);
                mbase[(nt * 8 + (c16 >> 1)) * 64 + wpix] = pk;
            }
        }
    }
}

// ---------------- kernel 3: reassembly (merged sp rows, pk_fma, nontemporal out) ----------------
__global__ __launch_bounds__(256) void reassemble(const float* __restrict__ x,
                                                  const unsigned* __restrict__ maskP,
                                                  float* __restrict__ out) {
    int lane = threadIdx.x & 63;       // = w
    int cq   = threadIdx.x >> 6;       // 0..3, wave-uniform
    int b    = blockIdx.x;
    int bs   = (b & 7) * 256 + (b >> 3);   // bijective: 2048 = 8*256
    int cgb  = bs & 3;
    int h    = (bs >> 2) & 63;
    int n    = bs >> 8;
    int c0   = cgb * 64 + cq * 16;

    const unsigned* mrow = maskP + ((size_t)n * 64 + h) * 3200 + lane;

    int   yy[5];
    float vmy[5], vmx[5];
#pragma unroll
    for (int d = 0; d < 5; d++) {
        int y  = h + d - 2;
        int xc = lane + d - 2;
        yy[d]  = min(max(y, 0), 63) * 64;
        vmy[d] = ((unsigned)y  < 64u) ? 1.f : 0.f;
        vmx[d] = ((unsigned)xc < 64u) ? 1.f : 0.f;
    }

    // msk2[2t]   = (row0col0,row0col1) * fold,  msk2[2t+1] = (row1col0,row1col1) * fold
    f32x2 msk2[50];
#pragma unroll
    for (int t = 0; t < 25; t++) {
        float f = vmy[t / 5] * vmx[t % 5];
        unsigned u0 = mrow[(2 * t + 0) * 64];
        unsigned u1 = mrow[(2 * t + 1) * 64];
        f32x2 m01, m23;
        m01.x = bf_lo(u0); m01.y = bf_hi(u0);
        m23.x = bf_lo(u1); m23.y = bf_hi(u1);
        msk2[2 * t + 0] = m01 * f;
        msk2[2 * t + 1] = m23 * f;
    }

    int idxm2 = ((lane - 2) & 63) << 2;
    int idxm1 = ((lane - 1) & 63) << 2;
    int idxp1 = ((lane + 1) & 63) << 2;
    int idxp2 = ((lane + 2) & 63) << 2;

    const float* xbase = x + ((size_t)(n * CI + c0)) * 4096 + lane;
    float*       obase = out + ((size_t)(n * CI + c0) * 128 + 2 * h) * 128 + 2 * lane;

    float ra[5], rb[5];
    unsigned pk[5];
#pragma unroll
    for (int d = 0; d < 5; d++) {
        ra[d] = xbase[yy[d]];
        rb[d] = xbase[4096 + yy[d]];
        pk[d] = cvt_pk_bf16(ra[d], rb[d]);
    }

    for (int p = 0; p < 8; p++) {
        const float* xn = xbase + (size_t)((p < 7) ? (2 * p + 2) : 0) * 4096;
        float na[5], nb[5];
#pragma unroll
        for (int d = 0; d < 5; d++) {
            na[d] = xn[yy[d]];
            nb[d] = xn[4096 + yy[d]];
        }

        f32x2 A0 = {0.f, 0.f}, A1 = {0.f, 0.f};   // rows 0,1 for channel A (cols packed)
        f32x2 B0 = {0.f, 0.f}, B1 = {0.f, 0.f};   // rows 0,1 for channel B
#pragma unroll
        for (int d = 0; d < 5; d++) {
            int pv = (int)pk[d];
            int sm2 = __builtin_amdgcn_ds_bpermute(idxm2, pv);
            int sm1 = __builtin_amdgcn_ds_bpermute(idxm1, pv);
            int sp1 = __builtin_amdgcn_ds_bpermute(idxp1, pv);
            int sp2 = __builtin_amdgcn_ds_bpermute(idxp2, pv);
            f32x2 s[5];
            s[0].x = bf_lo((unsigned)sm2); s[0].y = bf_hi((unsigned)sm2);
            s[1].x = bf_lo((unsigned)sm1); s[1].y = bf_hi((unsigned)sm1);
            s[2].x = ra[d];                s[2].y = rb[d];
            s[3].x = bf_lo((unsigned)sp1); s[3].y = bf_hi((unsigned)sp1);
            s[4].x = bf_lo((unsigned)sp2); s[4].y = bf_hi((unsigned)sp2);
            const f32x2* mk2 = msk2 + d * 10;
#pragma unroll
            for (int k = 0; k < 5; k++) {
                pk_fma_lo(A0, mk2[2 * k + 0], s[k]);   // chA: rows 0
                pk_fma_lo(A1, mk2[2 * k + 1], s[k]);   // chA: rows 1
                pk_fma_hi(B0, mk2[2 * k + 0], s[k]);   // chB: rows 0
                pk_fma_hi(B1, mk2[2 * k + 1], s[k]);   // chB: rows 1
            }
        }
        float* opa = obase + (size_t)(2 * p) * 16384;
        float* opb = opa + 16384;
        nt_store2(opa, A0);
        nt_store2(opa + 128, A1);
        nt_store2(opb, B0);
        nt_store2(opb + 128, B1);

#pragma unroll
        for (int d = 0; d < 5; d++) {
            ra[d] = na[d];
            rb[d] = nb[d];
            pk[d] = cvt_pk_bf16(na[d], nb[d]);
        }
    }
}

extern "C" void kernel_launch(void* const* d_in, const int* in_sizes, int n_in,
                              void* d_out, int out_size, void* d_ws, size_t ws_size,
                              hipStream_t stream) {
    const float* x      = (const float*)d_in[0];
    const float* w_comp = (const float*)d_in[1];
    const float* b_comp = (const float*)d_in[2];
    const float* w_enc  = (const float*)d_in[3];
    const float* b_enc  = (const float*)d_in[4];
    float* out = (float*)d_out;

    // workspace layout (bytes)
    char* ws = (char*)d_ws;
    float*          zp    = (float*)(ws + 0);                 // 256 B zeros
    unsigned short* wA    = (unsigned short*)(ws + 256);      // 32768 B
    unsigned short* Bp    = (unsigned short*)(ws + 33024);    // 129024 B
    unsigned short* comp  = (unsigned short*)(ws + 162048);   // 4 MB
    unsigned*       maskP = (unsigned*)(ws + 4356352);        // 6.55 MB
    // total ~11 MB

    prep_small<<<64, 256, 0, stream>>>(w_comp, wA, zp);
    conv1x1_mfma<<<1024 + 1008, 64, 0, stream>>>(x, wA, b_comp, w_enc, comp, Bp);
    conv3x3_mfma<<<512, 256, 0, stream>>>(comp, Bp, b_enc, zp, maskP);
    reassemble<<<2048, 256, 0, stream>>>(x, maskP, out);
}

// Round 19
// 60.984 us; speedup vs baseline: 1.2176x; 1.0801x over previous
//
#include <hip/hip_runtime.h>

// CARAFE: x(8,256,64,64) fp32 — BISECTION: R16's verified k1 (prep_small + wA) +
// R18's fused k2 (conv3x3 LDS-staged + softmax -> dedicated mask LDS + reassembly).
// K=5, G=1, S=2.  mask LDS: [n2(50)][65] uint, n2=2t+spq, pair=(sp=2spq,2spq+1) bf16.

#define CI 256

typedef __attribute__((ext_vector_type(8))) short bf16x8;
typedef __attribute__((ext_vector_type(4))) float f32x4;
typedef __attribute__((ext_vector_type(2))) float f32x2;

__device__ inline unsigned short f2bf(float f) {
    unsigned u = __float_as_uint(f);
    unsigned r = (u + 0x7FFF + ((u >> 16) & 1)) >> 16;
    return (unsigned short)r;
}

__device__ inline unsigned cvt_pk_bf16(float lo, float hi) {
    unsigned r;
    asm("v_cvt_pk_bf16_f32 %0, %1, %2" : "=v"(r) : "v"(lo), "v"(hi));
    return r;
}

__device__ inline float bf_lo(unsigned u) { return __int_as_float(u << 16); }
__device__ inline float bf_hi(unsigned u) { return __int_as_float(u & 0xffff0000u); }

// acc.lo += m.lo * s.lo ; acc.hi += m.hi * s.lo   (broadcast s.lo)
__device__ inline void pk_fma_lo(f32x2& acc, f32x2 m, f32x2 s) {
    asm("v_pk_fma_f32 %0, %1, %2, %0 op_sel_hi:[1,0,1]" : "+v"(acc) : "v"(m), "v"(s));
}
// acc.lo += m.lo * s.hi ; acc.hi += m.hi * s.hi   (broadcast s.hi)
__device__ inline void pk_fma_hi(f32x2& acc, f32x2 m, f32x2 s) {
    asm("v_pk_fma_f32 %0, %1, %2, %0 op_sel:[0,1,0] op_sel_hi:[1,1,1]" : "+v"(acc) : "v"(m), "v"(s));
}

__device__ inline void nt_store2(float* p, f32x2 v) {
    __builtin_nontemporal_store(__builtin_bit_cast(unsigned long long, v),
                                (unsigned long long*)p);
}

// ---------------- kernel 0: small prep (wA, zp — exactly R16's) ----------------
__global__ __launch_bounds__(256) void prep_small(const float* __restrict__ w_comp,
                                                  unsigned short* __restrict__ wA,
                                                  float* __restrict__ zp) {
    int i = blockIdx.x * 256 + threadIdx.x;
    if (i < 64) zp[i] = 0.f;
    if (i < 64 * 256) wA[i] = f2bf(w_comp[i]);
}

// ---------------- kernel 1: 1x1 conv via MFMA, 32 px/wave (exactly R16's) ----------------
__global__ __launch_bounds__(64) void conv1x1_mfma(const float* __restrict__ x,
                                                   const unsigned short* __restrict__ wA,
                                                   const float* __restrict__ b_comp,
                                                   const float* __restrict__ w_enc,
                                                   unsigned short* __restrict__ comp,
                                                   unsigned short* __restrict__ Bp) {
    int l = threadIdx.x;
    int b = blockIdx.x;

    if (b >= 1024) {
        int idx = (b - 1024) * 64 + l;      // 1008*64 = 64512 = 72*112*8
        int j = idx & 7;
        int n = (idx >> 3) % 112;
        int g = idx / (112 * 8);
        int k = g * 8 + j;
        int tap = k >> 6;
        int c = k & 63;
        float v = (n < 100) ? w_enc[n * 576 + c * 9 + tap] : 0.f;
        Bp[idx] = f2bf(v);
        return;
    }

    int c16 = l & 15;
    int lq  = l >> 4;
    int bs  = (b & 7) * 128 + (b >> 3);   // bijective: 1024 = 8*128
    int P0  = bs * 32;
    int nimg = P0 >> 12;
    int hw   = P0 & 4095;

    const float* xp = x + (size_t)nimg * CI * 4096 + hw + c16;

    f32x4 acc[4][2];
#pragma unroll
    for (int mt = 0; mt < 4; mt++)
#pragma unroll
        for (int pt = 0; pt < 2; pt++) acc[mt][pt] = f32x4{0.f, 0.f, 0.f, 0.f};

#pragma unroll
    for (int ks = 0; ks < 8; ks++) {
        int k0 = ks * 32 + lq * 8;
        float v0[8], v1[8];
#pragma unroll
        for (int j = 0; j < 8; j++) {
            const float* pj = xp + (size_t)(k0 + j) * 4096;
            v0[j] = pj[0];
            v1[j] = pj[16];
        }
        bf16x8 xb0, xb1;
#pragma unroll
        for (int j = 0; j < 8; j++) {
            xb0[j] = (short)f2bf(v0[j]);
            xb1[j] = (short)f2bf(v1[j]);
        }
#pragma unroll
        for (int mt = 0; mt < 4; mt++) {
            bf16x8 wf = *(const bf16x8*)(wA + (mt * 16 + c16) * 256 + k0);
            acc[mt][0] = __builtin_amdgcn_mfma_f32_16x16x32_bf16(wf, xb0, acc[mt][0], 0, 0, 0);
            acc[mt][1] = __builtin_amdgcn_mfma_f32_16x16x32_bf16(wf, xb1, acc[mt][1], 0, 0, 0);
        }
    }

#pragma unroll
    for (int pt = 0; pt < 2; pt++) {
        unsigned short* cp = comp + (size_t)(P0 + pt * 16 + c16) * 64;
#pragma unroll
        for (int mt = 0; mt < 4; mt++) {
            int och0 = mt * 16 + lq * 4;
            float4 bb = *reinterpret_cast<const float4*>(b_comp + och0);
            unsigned u0 = f2bf(acc[mt][pt][0] + bb.x) | (f2bf(acc[mt][pt][1] + bb.y) << 16);
            unsigned u1 = f2bf(acc[mt][pt][2] + bb.z) | (f2bf(acc[mt][pt][3] + bb.w) << 16);
            reinterpret_cast<uint2*>(cp + och0)[0] = uint2{u0, u1};
        }
    }
}

// ---------------- kernel 2: FUSED conv3x3 + softmax + reassembly (exactly R18's) ----------------
__global__ __launch_bounds__(256) void conv3x3_reasm(const unsigned short* __restrict__ comp,
                                                     const unsigned short* __restrict__ Bp,
                                                     const float* __restrict__ b_enc,
                                                     const float* __restrict__ zp,
                                                     const float* __restrict__ x,
                                                     float* __restrict__ out) {
    __shared__ char Bs[2][3 * 7168];        // 43008 B staging
    __shared__ unsigned mask_lds[3250];     // 50*65*4 = 13000 B, dedicated

    int tid = threadIdx.x;
    int wv  = tid >> 6;          // 0..3 (wave id)
    int l   = tid & 63;
    int c16 = l & 15;
    int lq  = l >> 4;
    int b   = blockIdx.x;
    int bs  = (b & 7) * 64 + (b >> 3);   // bijective: 512 = 8*64 -> XCD owns image
    int nimg = bs >> 6;
    int h    = bs & 63;
    int w0   = wv * 16;

    const char* cbase = (const char*)(comp + (size_t)nimg * 4096 * 64);
    const char* zpb   = (const char*)zp;
    const char* Bpb   = (const char*)Bp;

#define STAGEPH(s0_, buf_)                                                                \
    {                                                                                     \
        const char* src_ = Bpb + (s0_)*7168 + l * 16;                                     \
        for (int inst_ = wv; inst_ < 21; inst_ += 4) {                                    \
            __builtin_amdgcn_global_load_lds(                                             \
                (const __attribute__((address_space(1))) void*)(src_ + inst_ * 1024),     \
                (__attribute__((address_space(3))) void*)(&Bs[buf_][inst_ * 1024]),       \
                16, 0, 0);                                                                \
        }                                                                                 \
    }

    f32x4 acc[7];
#pragma unroll
    for (int nt = 0; nt < 7; nt++) acc[nt] = f32x4{0.f, 0.f, 0.f, 0.f};

    const int dyt[9] = {-1, -1, -1, 0, 0, 0, 1, 1, 1};
    const int dxt[9] = {-1, 0, 1, -1, 0, 1, -1, 0, 1};

    STAGEPH(0, 0);
    __syncthreads();

#pragma unroll
    for (int ph = 0; ph < 6; ph++) {
        int s0  = ph * 3;
        int cur = ph & 1;
        if (ph < 5) STAGEPH(s0 + 3, cur ^ 1);
        for (int ss = 0; ss < 3; ss++) {
            int s = s0 + ss;
            int tap = s >> 1, half = s & 1;
            int hh = h + dyt[tap];
            int ww = w0 + c16 + dxt[tap];
            const char* ap = ((unsigned)hh < 64u && (unsigned)ww < 64u)
                                 ? cbase + (hh * 64 + ww) * 128 : zpb;
            bf16x8 a = *(const bf16x8*)(ap + lq * 16 + half * 64);

            bf16x8 bf[7];
#pragma unroll
            for (int nt = 0; nt < 7; nt++)
                bf[nt] = *(const bf16x8*)(&Bs[cur][ss * 7168 + (lq * 112 + nt * 16 + c16) * 16]);
#pragma unroll
            for (int nt = 0; nt < 7; nt++)
                acc[nt] = __builtin_amdgcn_mfma_f32_16x16x32_bf16(a, bf[nt], acc[nt], 0, 0, 0);
        }
        __syncthreads();
    }
#undef STAGEPH

    // softmax epilogue -> packed pairs into dedicated mask_lds (stride 65)
    {
        float bias[7];
#pragma unroll
        for (int nt = 0; nt < 7; nt++) {
            int n = nt * 16 + c16;
            bias[nt] = (n < 100) ? b_enc[n] : 0.f;
        }
        int nvalid = (c16 < 4) ? 7 : 6;

#pragma unroll
        for (int r = 0; r < 4; r++) {
            float v[7];
#pragma unroll
            for (int nt = 0; nt < 7; nt++) v[nt] = acc[nt][r] + bias[nt];
            float m = v[0];
#pragma unroll
            for (int nt = 1; nt < 7; nt++) if (nt < nvalid) m = fmaxf(m, v[nt]);
            m = fmaxf(m, __shfl_xor(m, 4));
            m = fmaxf(m, __shfl_xor(m, 8));
            float e[7];
            float s = 0.f;
#pragma unroll
            for (int nt = 0; nt < 7; nt++) {
                e[nt] = (nt < nvalid) ? __expf(v[nt] - m) : 0.f;
                s += e[nt];
            }
            s += __shfl_xor(s, 4);
            s += __shfl_xor(s, 8);
            float inv = 1.f / s;
            int wpix = w0 + lq * 4 + r;
#pragma unroll
            for (int nt = 0; nt < 7; nt++) {
                float mine = (nt < nvalid) ? e[nt] * inv : 0.f;
                float part = __shfl_xor(mine, 1);
                if (((c16 & 1) == 0) && (nt * 16 + c16) < 100) {
                    unsigned pk = cvt_pk_bf16(mine, part);
                    mask_lds[(nt * 8 + (c16 >> 1)) * 65 + wpix] = pk;
                }
            }
        }
    }
    __syncthreads();   // mask complete in LDS

    // ---- phase 2: reassembly. wave wv owns channels [wv*64, wv*64+64) ----
    int c0 = wv * 64;
    const unsigned* mrow = mask_lds + l;

    int   yy[5];
    float vmy[5], vmx[5];
#pragma unroll
    for (int d = 0; d < 5; d++) {
        int y  = h + d - 2;
        int xc = l + d - 2;
        yy[d]  = min(max(y, 0), 63) * 64;
        vmy[d] = ((unsigned)y  < 64u) ? 1.f : 0.f;
        vmx[d] = ((unsigned)xc < 64u) ? 1.f : 0.f;
    }

    f32x2 msk2[50];
#pragma unroll
    for (int t = 0; t < 25; t++) {
        float f = vmy[t / 5] * vmx[t % 5];
        unsigned u0 = mrow[(2 * t + 0) * 65];
        unsigned u1 = mrow[(2 * t + 1) * 65];
        f32x2 m01, m23;
        m01.x = bf_lo(u0); m01.y = bf_hi(u0);
        m23.x = bf_lo(u1); m23.y = bf_hi(u1);
        msk2[2 * t + 0] = m01 * f;
        msk2[2 * t + 1] = m23 * f;
    }

    int idxm2 = ((l - 2) & 63) << 2;
    int idxm1 = ((l - 1) & 63) << 2;
    int idxp1 = ((l + 1) & 63) << 2;
    int idxp2 = ((l + 2) & 63) << 2;

    const float* xbase = x + ((size_t)(nimg * CI + c0)) * 4096 + l;
    float*       obase = out + ((size_t)(nimg * CI + c0) * 128 + 2 * h) * 128 + 2 * l;

    float ra[5], rb[5];
    unsigned pk[5];
#pragma unroll
    for (int d = 0; d < 5; d++) {
        ra[d] = xbase[yy[d]];
        rb[d] = xbase[4096 + yy[d]];
        pk[d] = cvt_pk_bf16(ra[d], rb[d]);
    }

    for (int p = 0; p < 32; p++) {
        const float* xn = xbase + (size_t)((p < 31) ? (2 * p + 2) : 0) * 4096;
        float na[5], nb[5];
#pragma unroll
        for (int d = 0; d < 5; d++) {
            na[d] = xn[yy[d]];
            nb[d] = xn[4096 + yy[d]];
        }

        f32x2 A0 = {0.f, 0.f}, A1 = {0.f, 0.f};
        f32x2 B0 = {0.f, 0.f}, B1 = {0.f, 0.f};
#pragma unroll
        for (int d = 0; d < 5; d++) {
            int pv = (int)pk[d];
            int sm2 = __builtin_amdgcn_ds_bpermute(idxm2, pv);
            int sm1 = __builtin_amdgcn_ds_bpermute(idxm1, pv);
            int sp1 = __builtin_amdgcn_ds_bpermute(idxp1, pv);
            int sp2 = __builtin_amdgcn_ds_bpermute(idxp2, pv);
            f32x2 s[5];
            s[0].x = bf_lo((unsigned)sm2); s[0].y = bf_hi((unsigned)sm2);
            s[1].x = bf_lo((unsigned)sm1); s[1].y = bf_hi((unsigned)sm1);
            s[2].x = ra[d];                s[2].y = rb[d];
            s[3].x = bf_lo((unsigned)sp1); s[3].y = bf_hi((unsigned)sp1);
            s[4].x = bf_lo((unsigned)sp2); s[4].y = bf_hi((unsigned)sp2);
            const f32x2* mk2 = msk2 + d * 10;
#pragma unroll
            for (int k = 0; k < 5; k++) {
                pk_fma_lo(A0, mk2[2 * k + 0], s[k]);
                pk_fma_lo(A1, mk2[2 * k + 1], s[k]);
                pk_fma_hi(B0, mk2[2 * k + 0], s[k]);
                pk_fma_hi(B1, mk2[2 * k + 1], s[k]);
            }
        }
        float* opa = obase + (size_t)(2 * p) * 16384;
        float* opb = opa + 16384;
        nt_store2(opa, A0);
        nt_store2(opa + 128, A1);
        nt_store2(opb, B0);
        nt_store2(opb + 128, B1);

#pragma unroll
        for (int d = 0; d < 5; d++) {
            ra[d] = na[d];
            rb[d] = nb[d];
            pk[d] = cvt_pk_bf16(na[d], nb[d]);
        }
    }
}

extern "C" void kernel_launch(void* const* d_in, const int* in_sizes, int n_in,
                              void* d_out, int out_size, void* d_ws, size_t ws_size,
                              hipStream_t stream) {
    const float* x      = (const float*)d_in[0];
    const float* w_comp = (const float*)d_in[1];
    const float* b_comp = (const float*)d_in[2];
    const float* w_enc  = (const float*)d_in[3];
    const float* b_enc  = (const float*)d_in[4];
    float* out = (float*)d_out;

    // workspace layout (bytes) — R16's
    char* ws = (char*)d_ws;
    float*          zp   = (float*)(ws + 0);                 // 256 B zeros
    unsigned short* wA   = (unsigned short*)(ws + 256);      // 32768 B
    unsigned short* Bp   = (unsigned short*)(ws + 33024);    // 129024 B
    unsigned short* comp = (unsigned short*)(ws + 162048);   // 4 MB
    // total ~4.3 MB

    prep_small<<<64, 256, 0, stream>>>(w_comp, wA, zp);
    conv1x1_mfma<<<1024 + 1008, 64, 0, stream>>>(x, wA, b_comp, w_enc, comp, Bp);
    conv3x3_reasm<<<512, 256, 0, stream>>>(comp, Bp, b_enc, zp, x, out);
}